// Round 1
// baseline (280.116 us; speedup 1.0000x reference)
//
#include <hip/hip_runtime.h>
#include <math.h>

#define L 2048
#define BATCH 8
#define NSPLIT 32                    // col-partial slabs per batch
#define ROWS_PER_SPLIT (L / NSPLIT)  // 64
#define SENT -1e30f
#define EPSF 1e-8f

// online softmax update with a new element x (x is already scaled by 1/TAU)
__device__ __forceinline__ void onl_upd(float& m, float& s, float x) {
    if (x > m) { s = s * __expf(m - x) + 1.0f; m = x; }  // exp(SENT-x) underflows to 0
    else       { s += __expf(x - m); }
}

// merge two online (max,sum) pairs; safe when either/both are (SENT, 0)
__device__ __forceinline__ void onl_merge(float& m, float& s, float m2, float s2) {
    float M = fmaxf(m, m2);
    s = s * __expf(m - M) + s2 * __expf(m2 - M);
    m = M;
}

__global__ __launch_bounds__(256) void row_stats_k(
    const float* __restrict__ sim, const int* __restrict__ lengths,
    float* __restrict__ rmax, float* __restrict__ rinv) {
  const int row = blockIdx.x;        // b*L + i
  const int b = row >> 11;
  const int len1 = lengths[2 * b + 1];
  const float* p = sim + (size_t)row * L;
  const int tid = threadIdx.x;
  float m = SENT, s = 0.0f;
#pragma unroll
  for (int ph = 0; ph < 2; ++ph) {
    const int j = ph * 1024 + tid * 4;
    float4 v = *reinterpret_cast<const float4*>(p + j);
    if (j + 3 < len1) {
      onl_upd(m, s, v.x * 2.0f); onl_upd(m, s, v.y * 2.0f);
      onl_upd(m, s, v.z * 2.0f); onl_upd(m, s, v.w * 2.0f);
    } else {
      if (j + 0 < len1) onl_upd(m, s, v.x * 2.0f);
      if (j + 1 < len1) onl_upd(m, s, v.y * 2.0f);
      if (j + 2 < len1) onl_upd(m, s, v.z * 2.0f);
      if (j + 3 < len1) onl_upd(m, s, v.w * 2.0f);
    }
  }
#pragma unroll
  for (int off = 32; off > 0; off >>= 1) {
    float m2 = __shfl_xor(m, off, 64);
    float s2 = __shfl_xor(s, off, 64);
    onl_merge(m, s, m2, s2);
  }
  __shared__ float smx[4], ssm[4];
  const int wave = tid >> 6, lane = tid & 63;
  if (lane == 0) { smx[wave] = m; ssm[wave] = s; }
  __syncthreads();
  if (tid == 0) {
#pragma unroll
    for (int w = 1; w < 4; ++w) onl_merge(m, s, smx[w], ssm[w]);
    rmax[row] = m;
    rinv[row] = 1.0f / s;
  }
}

__global__ __launch_bounds__(256) void col_partial_k(
    const float* __restrict__ sim, const int* __restrict__ lengths,
    float* __restrict__ pmax, float* __restrict__ psum) {
  const int b = blockIdx.z;
  const int len0 = lengths[2 * b];
  const int j = (blockIdx.x << 10) + threadIdx.x * 4;
  const int i0 = blockIdx.y * ROWS_PER_SPLIT;
  const int iend = min(i0 + ROWS_PER_SPLIT, len0);
  float4 m = make_float4(SENT, SENT, SENT, SENT);
  float4 s = make_float4(0.f, 0.f, 0.f, 0.f);
  const float* p = sim + ((size_t)b * L + i0) * L + j;
  for (int i = i0; i < iend; ++i, p += L) {
    float4 v = *reinterpret_cast<const float4*>(p);
    onl_upd(m.x, s.x, v.x * 2.0f);
    onl_upd(m.y, s.y, v.y * 2.0f);
    onl_upd(m.z, s.z, v.z * 2.0f);
    onl_upd(m.w, s.w, v.w * 2.0f);
  }
  const size_t o = (size_t)(b * NSPLIT + blockIdx.y) * L + j;
  *reinterpret_cast<float4*>(pmax + o) = m;
  *reinterpret_cast<float4*>(psum + o) = s;
}

__global__ __launch_bounds__(256) void col_merge_k(
    const float* __restrict__ pmax, const float* __restrict__ psum,
    float* __restrict__ cmax, float* __restrict__ cinv) {
  const int idx = blockIdx.x * 256 + threadIdx.x;  // b*L + j
  const int b = idx >> 11, j = idx & (L - 1);
  float m = SENT, s = 0.0f;
#pragma unroll 4
  for (int c = 0; c < NSPLIT; ++c) {
    const size_t o = (size_t)(b * NSPLIT + c) * L + j;
    onl_merge(m, s, pmax[o], psum[o]);
  }
  cmax[idx] = m;
  cinv[idx] = 1.0f / s;
}

__global__ __launch_bounds__(256) void finalize_k(
    const float* __restrict__ sim, const int* __restrict__ lengths,
    const float* __restrict__ rmax, const float* __restrict__ rinv,
    const float* __restrict__ cmax, const float* __restrict__ cinv,
    float* __restrict__ out) {
  const int row = blockIdx.y;        // b*L + i
  const int b = row >> 11, i = row & (L - 1);
  const int len0 = lengths[2 * b], len1 = lengths[2 * b + 1];
  const int j = (blockIdx.x << 10) + threadIdx.x * 4;
  const size_t off = (size_t)row * L + j;
  float4 o;
  if (i >= len0) {
    o = make_float4(0.f, 0.f, 0.f, 0.f);
  } else {
    const float rm = rmax[row], ri = rinv[row];
    float4 v = *reinterpret_cast<const float4*>(sim + off);
    const size_t co = (size_t)b * L + j;
    float4 cm = *reinterpret_cast<const float4*>(cmax + co);
    float4 ci = *reinterpret_cast<const float4*>(cinv + co);
    o.x = (j + 0 < len1) ? sqrtf(EPSF + __expf(4.0f * v.x - rm - cm.x) * ri * ci.x) : 0.0f;
    o.y = (j + 1 < len1) ? sqrtf(EPSF + __expf(4.0f * v.y - rm - cm.y) * ri * ci.y) : 0.0f;
    o.z = (j + 2 < len1) ? sqrtf(EPSF + __expf(4.0f * v.z - rm - cm.z) * ri * ci.z) : 0.0f;
    o.w = (j + 3 < len1) ? sqrtf(EPSF + __expf(4.0f * v.w - rm - cm.w) * ri * ci.w) : 0.0f;
  }
  *reinterpret_cast<float4*>(out + off) = o;
}

extern "C" void kernel_launch(void* const* d_in, const int* in_sizes, int n_in,
                              void* d_out, int out_size, void* d_ws, size_t ws_size,
                              hipStream_t stream) {
  const float* sim = (const float*)d_in[0];
  const int* lengths = (const int*)d_in[1];
  float* out = (float*)d_out;
  float* ws = (float*)d_ws;

  const int NR = BATCH * L;  // 16384 rows (= cols per batch * batches too)
  float* rmax = ws;
  float* rinv = ws + NR;
  float* cmax = ws + 2 * (size_t)NR;
  float* cinv = ws + 3 * (size_t)NR;
  float* pmax = ws + 4 * (size_t)NR;
  float* psum = pmax + (size_t)BATCH * NSPLIT * L;
  // total ws use: 4*16384 + 2*8*32*2048 floats = ~4.25 MiB

  hipLaunchKernelGGL(row_stats_k, dim3(NR), dim3(256), 0, stream,
                     sim, lengths, rmax, rinv);
  hipLaunchKernelGGL(col_partial_k, dim3(2, NSPLIT, BATCH), dim3(256), 0, stream,
                     sim, lengths, pmax, psum);
  hipLaunchKernelGGL(col_merge_k, dim3(NR / 256), dim3(256), 0, stream,
                     pmax, psum, cmax, cinv);
  hipLaunchKernelGGL(finalize_k, dim3(2, NR), dim3(256), 0, stream,
                     sim, lengths, rmax, rinv, cmax, cinv, out);
}

// Round 2
// 244.702 us; speedup vs baseline: 1.1447x; 1.1447x over previous
//
#include <hip/hip_runtime.h>
#include <math.h>

#define L 2048
#define BATCH 8
#define RPS 32               // rows per slab in stats kernel
#define NSPLIT (L / RPS)     // 64 column-partial slabs per batch
#define EPSF 1e-8f
#define C2 2.885390081777927f   // 2/ln2  : exp(2x)  = exp2(x*C2)
#define C4 5.770780163555854f   // 4/ln2  : exp(4x)  = exp2(x*C4)

__device__ __forceinline__ float fexp2(float x) {
  return __builtin_amdgcn_exp2f(x);   // v_exp_f32
}

// One block = full 2048-col x 32-row slab. 512 threads, thread t owns cols 4t..4t+3.
// Produces: complete row sums (as rinv) for its 32 rows, and one column-partial
// vector (sum over its 32 rows) per slab.
__global__ __launch_bounds__(512) void stats_k(
    const float* __restrict__ sim, const int* __restrict__ lengths,
    float* __restrict__ rinv, float* __restrict__ pcol) {
  const int b = blockIdx.y;
  const int islab = blockIdx.x;
  const int len0 = lengths[2 * b], len1 = lengths[2 * b + 1];
  const int tid = threadIdx.x;
  const int j = tid * 4;
  const int i0 = islab * RPS;
  const int iend = min(i0 + RPS, len0);   // rows >= len0 contribute nothing

  // column-validity mask, fixed per thread (branch-free accumulation)
  float4 msk;
  msk.x = (j + 0 < len1) ? 1.f : 0.f;
  msk.y = (j + 1 < len1) ? 1.f : 0.f;
  msk.z = (j + 2 < len1) ? 1.f : 0.f;
  msk.w = (j + 3 < len1) ? 1.f : 0.f;

  float4 cacc = make_float4(0.f, 0.f, 0.f, 0.f);
  __shared__ float rowpart[RPS][8];       // per-row, per-wave partial row sums
  const int wave = tid >> 6, lane = tid & 63;

  const float* p = sim + ((size_t)b * L + i0) * L + j;
  for (int i = i0; i < iend; ++i, p += L) {
    float4 v = *reinterpret_cast<const float4*>(p);
    float4 e;
    e.x = fexp2(v.x * C2) * msk.x;
    e.y = fexp2(v.y * C2) * msk.y;
    e.z = fexp2(v.z * C2) * msk.z;
    e.w = fexp2(v.w * C2) * msk.w;
    cacc.x += e.x; cacc.y += e.y; cacc.z += e.z; cacc.w += e.w;
    float r = (e.x + e.y) + (e.z + e.w);
#pragma unroll
    for (int off = 1; off < 64; off <<= 1) r += __shfl_xor(r, off, 64);
    if (lane == 0) rowpart[i - i0][wave] = r;
  }
  __syncthreads();

  if (tid < RPS) {
    const int i = i0 + tid;
    if (i < len0) {
      float s = 0.f;
#pragma unroll
      for (int w = 0; w < 8; ++w) s += rowpart[tid][w];
      rinv[b * L + i] = 1.0f / s;
    }
  }
  const size_t o = (size_t)(b * NSPLIT + islab) * L + j;
  *reinterpret_cast<float4*>(pcol + o) = cacc;
}

__global__ __launch_bounds__(256) void col_merge_k(
    const float* __restrict__ pcol, float* __restrict__ cinv) {
  const int idx = blockIdx.x * 256 + threadIdx.x;  // b*L + j
  const int b = idx >> 11, j = idx & (L - 1);
  const float* p = pcol + (size_t)b * NSPLIT * L + j;
  float s = 0.f;
#pragma unroll 8
  for (int c = 0; c < NSPLIT; ++c) s += p[(size_t)c * L];
  cinv[idx] = 1.0f / s;   // inf for j >= len1: unused (finalize masks)
}

__global__ __launch_bounds__(256) void finalize_k(
    const float* __restrict__ sim, const int* __restrict__ lengths,
    const float* __restrict__ rinv, const float* __restrict__ cinv,
    float* __restrict__ out) {
  const int row = blockIdx.y;        // b*L + i
  const int b = row >> 11, i = row & (L - 1);
  const int len0 = lengths[2 * b], len1 = lengths[2 * b + 1];
  const int j = (blockIdx.x << 10) + threadIdx.x * 4;
  const size_t off = (size_t)row * L + j;
  float4 o;
  if (i >= len0) {                   // block-uniform branch
    o = make_float4(0.f, 0.f, 0.f, 0.f);
  } else {
    const float ri = rinv[row];
    float4 v = *reinterpret_cast<const float4*>(sim + off);
    float4 ci = *reinterpret_cast<const float4*>(cinv + (size_t)b * L + j);
    o.x = (j + 0 < len1) ? sqrtf(EPSF + fexp2(v.x * C4) * ri * ci.x) : 0.f;
    o.y = (j + 1 < len1) ? sqrtf(EPSF + fexp2(v.y * C4) * ri * ci.y) : 0.f;
    o.z = (j + 2 < len1) ? sqrtf(EPSF + fexp2(v.z * C4) * ri * ci.z) : 0.f;
    o.w = (j + 3 < len1) ? sqrtf(EPSF + fexp2(v.w * C4) * ri * ci.w) : 0.f;
  }
  *reinterpret_cast<float4*>(out + off) = o;
}

extern "C" void kernel_launch(void* const* d_in, const int* in_sizes, int n_in,
                              void* d_out, int out_size, void* d_ws, size_t ws_size,
                              hipStream_t stream) {
  const float* sim = (const float*)d_in[0];
  const int* lengths = (const int*)d_in[1];
  float* out = (float*)d_out;
  float* ws = (float*)d_ws;

  const int NR = BATCH * L;  // 16384
  float* rinv = ws;
  float* cinv = ws + NR;
  float* pcol = ws + 2 * (size_t)NR;
  // ws use: 2*16384 + 8*64*2048 floats = ~4.1 MiB

  hipLaunchKernelGGL(stats_k, dim3(NSPLIT, BATCH), dim3(512), 0, stream,
                     sim, lengths, rinv, pcol);
  hipLaunchKernelGGL(col_merge_k, dim3(NR / 256), dim3(256), 0, stream,
                     pcol, cinv);
  hipLaunchKernelGGL(finalize_k, dim3(2, NR), dim3(256), 0, stream,
                     sim, lengths, rinv, cinv, out);
}

// Round 3
// 244.466 us; speedup vs baseline: 1.1458x; 1.0010x over previous
//
#include <hip/hip_runtime.h>
#include <math.h>

#define L 2048
#define BATCH 8
#define RPS 16               // rows per block in stats kernel (4 waves x 4 rows)
#define NSPLIT (L / RPS)     // 128 column-partial slabs per batch
#define EPSF 1e-8f
#define C2 2.885390081777927f   // 2/ln2 : exp(2x) = exp2(x*C2)
#define C4 5.770780163555854f   // 4/ln2 : exp(4x) = exp2(x*C4)

__device__ __forceinline__ float fexp2(float x) {
  return __builtin_amdgcn_exp2f(x);   // v_exp_f32
}

// Block = 256 threads (4 waves). Wave w owns rows i0+4w .. i0+4w+3 (whole rows).
// Per row: 8 unrolled steps of 1KB contiguous wave loads; row sum is a per-lane
// register accumulator reduced by ONE shuffle butterfly per row. Column sums are
// 32 per-lane registers (lane l, step s -> cols s*256 + 4l .. +3), merged across
// the 4 waves once per block via LDS.
__global__ __launch_bounds__(256) void stats_k(
    const float* __restrict__ sim, const int* __restrict__ lengths,
    float* __restrict__ rinv, float* __restrict__ pcol) {
  const int b = blockIdx.y;
  const int islab = blockIdx.x;
  const int len0 = lengths[2 * b], len1 = lengths[2 * b + 1];
  const int tid = threadIdx.x;
  const int wave = tid >> 6, lane = tid & 63;
  const int i0 = islab * RPS + wave * 4;
  const int jb = lane * 4;

  float4 cacc[8];
#pragma unroll
  for (int s = 0; s < 8; ++s) cacc[s] = make_float4(0.f, 0.f, 0.f, 0.f);

  for (int r = 0; r < 4; ++r) {
    const int i = i0 + r;
    if (i >= len0) break;              // wave-uniform exit; rows >= len0 contribute 0
    const float* p = sim + ((size_t)b * L + i) * L + jb;
    float racc = 0.f;
#pragma unroll
    for (int s = 0; s < 8; ++s) {
      float4 v = *reinterpret_cast<const float4*>(p + s * 256);
      float4 e;
      e.x = fexp2(v.x * C2); e.y = fexp2(v.y * C2);
      e.z = fexp2(v.z * C2); e.w = fexp2(v.w * C2);
      if (s >= 4) {                    // len1 >= 1024: steps 0-3 always valid
        const int j = s * 256 + jb;
        if (j + 0 >= len1) e.x = 0.f;
        if (j + 1 >= len1) e.y = 0.f;
        if (j + 2 >= len1) e.z = 0.f;
        if (j + 3 >= len1) e.w = 0.f;
      }
      racc += (e.x + e.y) + (e.z + e.w);
      cacc[s].x += e.x; cacc[s].y += e.y; cacc[s].z += e.z; cacc[s].w += e.w;
    }
#pragma unroll
    for (int off = 1; off < 64; off <<= 1) racc += __shfl_xor(racc, off, 64);
    if (lane == 0) rinv[(size_t)b * L + i] = 1.0f / racc;
  }

  __shared__ float cpart[4][2048];     // 32 KB
#pragma unroll
  for (int s = 0; s < 8; ++s)
    *reinterpret_cast<float4*>(&cpart[wave][s * 256 + jb]) = cacc[s];
  __syncthreads();

#pragma unroll
  for (int h = 0; h < 2; ++h) {
    const int c = h * 1024 + tid * 4;
    float4 a0 = *reinterpret_cast<const float4*>(&cpart[0][c]);
    float4 a1 = *reinterpret_cast<const float4*>(&cpart[1][c]);
    float4 a2 = *reinterpret_cast<const float4*>(&cpart[2][c]);
    float4 a3 = *reinterpret_cast<const float4*>(&cpart[3][c]);
    float4 o;
    o.x = (a0.x + a1.x) + (a2.x + a3.x);
    o.y = (a0.y + a1.y) + (a2.y + a3.y);
    o.z = (a0.z + a1.z) + (a2.z + a3.z);
    o.w = (a0.w + a1.w) + (a2.w + a3.w);
    *reinterpret_cast<float4*>(&pcol[(size_t)(b * NSPLIT + islab) * L + c]) = o;
  }
}

__global__ __launch_bounds__(128) void col_merge_k(
    const float* __restrict__ pcol, float* __restrict__ cinv) {
  const int idx = blockIdx.x * 128 + threadIdx.x;  // b*L + j
  const int b = idx >> 11, j = idx & (L - 1);
  const float* p = pcol + (size_t)b * NSPLIT * L + j;
  float s = 0.f;
#pragma unroll 16
  for (int c = 0; c < NSPLIT; ++c) s += p[(size_t)c * L];
  cinv[idx] = 1.0f / s;   // inf for j >= len1: discarded by finalize's select
}

__global__ __launch_bounds__(512) void finalize_k(
    const float* __restrict__ sim, const int* __restrict__ lengths,
    const float* __restrict__ rinv, const float* __restrict__ cinv,
    float* __restrict__ out) {
  const int row = blockIdx.x;          // b*L + i ; one block = one full row
  const int b = row >> 11, i = row & (L - 1);
  const int len0 = lengths[2 * b], len1 = lengths[2 * b + 1];
  const int j = threadIdx.x * 4;
  const size_t off = (size_t)row * L + j;
  float4 o;
  if (i >= len0) {                     // block-uniform branch: zero row
    o = make_float4(0.f, 0.f, 0.f, 0.f);
  } else {
    const float ri = rinv[row];
    float4 v = *reinterpret_cast<const float4*>(sim + off);
    float4 ci = *reinterpret_cast<const float4*>(cinv + ((size_t)b << 11) + j);
    o.x = (j + 0 < len1) ? sqrtf(EPSF + fexp2(v.x * C4) * ri * ci.x) : 0.f;
    o.y = (j + 1 < len1) ? sqrtf(EPSF + fexp2(v.y * C4) * ri * ci.y) : 0.f;
    o.z = (j + 2 < len1) ? sqrtf(EPSF + fexp2(v.z * C4) * ri * ci.z) : 0.f;
    o.w = (j + 3 < len1) ? sqrtf(EPSF + fexp2(v.w * C4) * ri * ci.w) : 0.f;
  }
  *reinterpret_cast<float4*>(out + off) = o;
}

extern "C" void kernel_launch(void* const* d_in, const int* in_sizes, int n_in,
                              void* d_out, int out_size, void* d_ws, size_t ws_size,
                              hipStream_t stream) {
  const float* sim = (const float*)d_in[0];
  const int* lengths = (const int*)d_in[1];
  float* out = (float*)d_out;
  float* ws = (float*)d_ws;

  const int NR = BATCH * L;  // 16384
  float* rinv = ws;
  float* cinv = ws + NR;
  float* pcol = ws + 2 * (size_t)NR;
  // ws use: 2*16384 + 8*128*2048 floats = ~8.1 MiB

  hipLaunchKernelGGL(stats_k, dim3(NSPLIT, BATCH), dim3(256), 0, stream,
                     sim, lengths, rinv, pcol);
  hipLaunchKernelGGL(col_merge_k, dim3(NR / 128), dim3(128), 0, stream,
                     pcol, cinv);
  hipLaunchKernelGGL(finalize_k, dim3(NR), dim3(512), 0, stream,
                     sim, lengths, rinv, cinv, out);
}